// Round 2
// baseline (165.473 us; speedup 1.0000x reference)
//
#include <hip/hip_runtime.h>

// LIF forward scan: u = 0.5*u + x[t] - 0.5*o ; o = (u - 0.5 > 0) ? 1 : 0
// x: [32, 8192, 200] f32, time contiguous. 262144 independent rows.
//
// R2 design: register-resident recurrence + prefetch.
//  - 256 rows/block; x staged through an XOR-swizzled [256][8] float4 LDS tile
//    so ALL LDS traffic is ds_read_b128/ds_write_b128.
//  - compute phase pulls the thread's whole 32-step chunk into 8 float4 regs,
//    runs the scan with zero memory ops, writes spikes back over the same regs.
//  - next chunk's global loads are issued right after the stage-in barrier, so
//    ~900-cycle HBM latency hides under the ~3200-cycle compute dep chain.
//  - thread<->slot mapping is bijective: the store phase reads exactly the
//    slots the same thread re-writes at the next stage-in -> only 2 barriers
//    per chunk.
// Arithmetic uses __f*_rn to forbid FMA contraction (bit-exact vs numpy order;
// a spike flip near threshold is absmax=1.0).

#define STEPS 200
#define RPB 256

__device__ __forceinline__ void lif_step(float& u, float& o, float xi) {
    float a = __fmul_rn(0.5f, u);
    float s = __fadd_rn(a, xi);
    float d = __fmul_rn(0.5f, o);
    u = __fsub_rn(s, d);
    o = (u > 0.5f) ? 1.0f : 0.0f;
}

// global -> regs, coalesced pattern: f = k*RPB+tid, r = f/N, c = f%N
template <int CSC>
__device__ __forceinline__ void gload(float4* v, const float* __restrict__ xb,
                                      int tid, int t0) {
    constexpr int N = CSC / 4;
#pragma unroll
    for (int k = 0; k < N; ++k) {
        int f = k * RPB + tid;
        int r = f / N;
        int c = f % N;
        v[k] = *reinterpret_cast<const float4*>(xb + r * STEPS + t0 + c * 4);
    }
}

// regs -> global, mirror of gload
template <int CSC>
__device__ __forceinline__ void gstore(const float4* v, float* __restrict__ ob,
                                       int tid, int t0) {
    constexpr int N = CSC / 4;
#pragma unroll
    for (int k = 0; k < N; ++k) {
        int f = k * RPB + tid;
        int r = f / N;
        int c = f % N;
        *reinterpret_cast<float4*>(ob + r * STEPS + t0 + c * 4) = v[k];
    }
}

// swizzled slot index: row r, col c -> r*N + (c ^ (r & (N-1)))
template <int CSC>
__device__ __forceinline__ void lds_put_pattern(const float4* v, float4* tile4, int tid) {
    constexpr int N = CSC / 4;
#pragma unroll
    for (int k = 0; k < N; ++k) {
        int f = k * RPB + tid;
        int r = f / N;
        int c = f % N;
        tile4[r * N + (c ^ (r & (N - 1)))] = v[k];
    }
}

template <int CSC>
__device__ __forceinline__ void lds_get_pattern(float4* v, const float4* tile4, int tid) {
    constexpr int N = CSC / 4;
#pragma unroll
    for (int k = 0; k < N; ++k) {
        int f = k * RPB + tid;
        int r = f / N;
        int c = f % N;
        v[k] = tile4[r * N + (c ^ (r & (N - 1)))];
    }
}

// thread tid owns tile row tid
template <int CSC>
__device__ __forceinline__ void lds_get_row(float4* rx, const float4* tile4, int tid) {
    constexpr int N = CSC / 4;
#pragma unroll
    for (int c = 0; c < N; ++c)
        rx[c] = tile4[tid * N + (c ^ (tid & (N - 1)))];
}

template <int CSC>
__device__ __forceinline__ void lds_put_row(const float4* rx, float4* tile4, int tid) {
    constexpr int N = CSC / 4;
#pragma unroll
    for (int c = 0; c < N; ++c)
        tile4[tid * N + (c ^ (tid & (N - 1)))] = rx[c];
}

// pure-register scan over the chunk; spikes overwrite the x regs in place
template <int CSC>
__device__ __forceinline__ void compute(float4* rx, float& u, float& o) {
    constexpr int N = CSC / 4;
#pragma unroll
    for (int k = 0; k < N; ++k) {
        float4 f4 = rx[k];
        lif_step(u, o, f4.x); float o0 = o;
        lif_step(u, o, f4.y); float o1 = o;
        lif_step(u, o, f4.z); float o2 = o;
        lif_step(u, o, f4.w); float o3 = o;
        rx[k] = make_float4(o0, o1, o2, o3);
    }
}

__global__ __launch_bounds__(RPB, 4) void lif_kernel(
    const float* __restrict__ x, float* __restrict__ out)
{
    __shared__ float4 tile4[RPB * 8];   // 32 KB
    const int tid = threadIdx.x;
    const long long row0 = (long long)blockIdx.x * RPB;
    const float* xb = x + row0 * STEPS;
    float* ob = out + row0 * STEPS;
    float u = 0.0f, o = 0.0f;

    float4 sA[8];   // staging regs (global in-flight target)
    float4 rx[8];   // row regs (x in, spikes out)
    float4 sv[8];   // store regs

    gload<32>(sA, xb, tid, 0);
#pragma unroll
    for (int ch = 0; ch < 6; ++ch) {
        lds_put_pattern<32>(sA, tile4, tid);
        __syncthreads();                       // x-tile ready; sA regs free
        if (ch < 5) gload<32>(sA, xb, tid, (ch + 1) * 32);   // prefetch next
        else        gload<8>(sA, xb, tid, 192);              // prefetch tail
        lds_get_row<32>(rx, tile4, tid);       // 8x ds_read_b128
        compute<32>(rx, u, o);                 // pure-register scan
        lds_put_row<32>(rx, tile4, tid);       // spikes back (own row, no race)
        __syncthreads();                       // spike-tile ready
        lds_get_pattern<32>(sv, tile4, tid);
        gstore<32>(sv, ob, tid, ch * 32);
        // no barrier: next lds_put_pattern writes exactly the slots this
        // thread just read (bijective mapping) -> same-wave DS ordering
    }
    __syncthreads();                           // tail uses a different mapping
    lds_put_pattern<8>(sA, tile4, tid);
    __syncthreads();
    lds_get_row<8>(rx, tile4, tid);
    compute<8>(rx, u, o);
    lds_put_row<8>(rx, tile4, tid);
    __syncthreads();
    lds_get_pattern<8>(sv, tile4, tid);
    gstore<8>(sv, ob, tid, 192);
}

extern "C" void kernel_launch(void* const* d_in, const int* in_sizes, int n_in,
                              void* d_out, int out_size, void* d_ws, size_t ws_size,
                              hipStream_t stream)
{
    const float* x = (const float*)d_in[0];
    float* out = (float*)d_out;
    int nrows = in_sizes[0] / STEPS;   // 262144
    int grid = nrows / RPB;            // 1024 blocks = 4 per CU, exact
    lif_kernel<<<grid, RPB, 0, stream>>>(x, out);
}

// Round 3
// 136.879 us; speedup vs baseline: 1.2089x; 1.2089x over previous
//
#include <hip/hip_runtime.h>

// LIF forward scan: u = 0.5*u + x[t] - 0.5*o ; o = (u - 0.5 > 0) ? 1 : 0
// x: [32, 8192, 200] f32, time contiguous. 262144 independent rows.
//
// R3 design: barrier-free, wave-private pipelines.
//  - Each WAVE owns 64 rows and a private 8 KB LDS slice; the row<->lane
//    transpose only needs intra-wave cooperation, so there are NO
//    __syncthreads at all. All 16 waves/CU run independent pipelines at
//    uncorrelated phases -> HBM latency hidden by TLP instead of in-block
//    prefetch (which spilled to scratch in R2: VGPR=52, +295MB HBM traffic).
//  - LDS slice [64 rows][N float4] XOR-swizzled (slot c ^ (r&(N-1))): the
//    staging writes, per-row reads, spike writes and store reads are all
//    bank-uniform (8 words/bank per wave access) -> conflict-free.
//  - Single rx[8] float4 array live (~50 VGPR): no scratch.
// Arithmetic uses __f*_rn to forbid FMA contraction (bit-exact vs numpy
// order; a spike flip near threshold is absmax=1.0).

#define STEPS 200
#define RPB 256          // threads per block (4 independent waves)

__device__ __forceinline__ void lif_step(float& u, float& o, float xi) {
    float a = __fmul_rn(0.5f, u);
    float s = __fadd_rn(a, xi);
    float d = __fmul_rn(0.5f, o);
    u = __fsub_rn(s, d);
    o = (u > 0.5f) ? 1.0f : 0.0f;
}

// One time-chunk of CS floats for this wave's 64 rows, entirely intra-wave.
template <int CS>
__device__ __forceinline__ void do_chunk(const float* __restrict__ xrow0,
                                         float* __restrict__ orow0,
                                         float4* __restrict__ slice4,
                                         int lane, int t0, float& u, float& o)
{
    constexpr int N = CS / 4;          // float4s per row-chunk
    // ---- stage in: coalesced global read -> swizzled LDS ----
    // inst k covers 8 (CS=32) complete 128B row-segments: fully-used lines
#pragma unroll
    for (int k = 0; k < N; ++k) {
        int f = k * 64 + lane;
        int r = f / N;                 // pow2 -> shift
        int c = f % N;
        float4 v = *reinterpret_cast<const float4*>(xrow0 + r * STEPS + t0 + c * 4);
        slice4[r * N + (c ^ (r & (N - 1)))] = v;
    }
    // ---- compute: lane owns row `lane`; pure-register scan ----
    float4 rx[N];
#pragma unroll
    for (int c = 0; c < N; ++c)
        rx[c] = slice4[lane * N + (c ^ (lane & (N - 1)))];
#pragma unroll
    for (int c = 0; c < N; ++c) {
        float4 f4 = rx[c];
        lif_step(u, o, f4.x); float o0 = o;
        lif_step(u, o, f4.y); float o1 = o;
        lif_step(u, o, f4.z); float o2 = o;
        lif_step(u, o, f4.w); float o3 = o;
        rx[c] = make_float4(o0, o1, o2, o3);
    }
#pragma unroll
    for (int c = 0; c < N; ++c)
        slice4[lane * N + (c ^ (lane & (N - 1)))] = rx[c];
    // ---- store out: swizzled LDS -> coalesced global write ----
#pragma unroll
    for (int k = 0; k < N; ++k) {
        int f = k * 64 + lane;
        int r = f / N;
        int c = f % N;
        float4 v = slice4[r * N + (c ^ (r & (N - 1)))];
        *reinterpret_cast<float4*>(orow0 + r * STEPS + t0 + c * 4) = v;
    }
}

__global__ __launch_bounds__(RPB, 4) void lif_kernel(
    const float* __restrict__ x, float* __restrict__ out)
{
    __shared__ float4 tile4[RPB * 8];            // 32 KB = 4 waves x 8 KB slices
    const int tid  = threadIdx.x;
    const int w    = tid >> 6;
    const int lane = tid & 63;
    const long long row0 = (long long)blockIdx.x * RPB + w * 64;
    const float* xb = x + row0 * STEPS;
    float* ob = out + row0 * STEPS;
    float4* slice4 = tile4 + w * 64 * 8;         // wave-private: no barriers needed
    float u = 0.0f, o = 0.0f;
    // 200 = 6*32 + 8
#pragma unroll
    for (int ch = 0; ch < 6; ++ch)
        do_chunk<32>(xb, ob, slice4, lane, ch * 32, u, o);
    do_chunk<8>(xb, ob, slice4, lane, 192, u, o);
}

extern "C" void kernel_launch(void* const* d_in, const int* in_sizes, int n_in,
                              void* d_out, int out_size, void* d_ws, size_t ws_size,
                              hipStream_t stream)
{
    const float* x = (const float*)d_in[0];
    float* out = (float*)d_out;
    int nrows = in_sizes[0] / STEPS;   // 262144
    int grid = nrows / RPB;            // 1024 blocks = 4 per CU, exact
    lif_kernel<<<grid, RPB, 0, stream>>>(x, out);
}